// Round 9
// baseline (201.926 us; speedup 1.0000x reference)
//
#include <hip/hip_runtime.h>

#define F_IN 165
#define HID  32
#define TROWS 32                        // rows per tile; N=500000 = 32*15625 exact
#define XBYTES (TROWS * F_IN * 4)       // 21120
#define XUNITS 21                       // unit 20 overreads 384B into next tile
#define BUFSZ  (XUNITS * 1024)          // 21504 (x only; h,c go to registers)
#define PYOFF  (2 * BUFSZ)              // 43008; +512 py -> 43520 B LDS

typedef __attribute__((ext_vector_type(8))) __bf16 bf16x8;
typedef __attribute__((ext_vector_type(4))) float  f32x4;

typedef __attribute__((address_space(1))) void as1_void;
typedef __attribute__((address_space(3))) void as3_void;

__device__ __forceinline__ void gload_lds16(const void* g, void* l) {
    __builtin_amdgcn_global_load_lds(
        reinterpret_cast<as1_void*>(reinterpret_cast<uintptr_t>(g)),
        reinterpret_cast<as3_void*>((uint32_t)reinterpret_cast<uintptr_t>(l)),
        16, 0, 0);
}

__device__ __forceinline__ float fast_sigmoid(float x) {
    return __builtin_amdgcn_rcpf(1.f + __builtin_amdgcn_exp2f(-1.4426950408889634f * x));
}
__device__ __forceinline__ float fast_tanh(float x) {
    return 1.f - 2.f * __builtin_amdgcn_rcpf(1.f + __builtin_amdgcn_exp2f(2.8853900817779268f * x));
}

// ---- workspace (prepacked): frag table 56 slots x 64 lanes x 16B; bias at +57344
#define FRAG_BYTES 57344

struct PrepParams {
    const float *W0, *W1, *W2, *W3;
    const float *Wc0, *Wc1, *Wc2, *Wc3;
    const float *b0, *b1, *b2, *b3;
    const float *bc0, *bc1, *bc2, *bc3;
    char* ws;
};

__global__ void gclstm_prep(PrepParams pp) {
    int t = blockIdx.x * 256 + threadIdx.x;
    if (t < 56 * 64) {
        int slot = t >> 6, l = t & 63;
        int ks = slot >> 3, g = (slot >> 1) & 3, hf = slot & 1;
        int cl = l & 15, q = l >> 4;
        const float* W = (ks < 6)
            ? (g==0 ? pp.W0  : g==1 ? pp.W1  : g==2 ? pp.W2  : pp.W3)
            : (g==0 ? pp.Wc0 : g==1 ? pp.Wc1 : g==2 ? pp.Wc2 : pp.Wc3);
        bf16x8 v;
#pragma unroll
        for (int j = 0; j < 8; ++j) {
            float f = 0.f;
            if (ks < 6) {
                int k = ks * 32 + q * 8 + j;
                if (k < F_IN) f = W[k * HID + hf * 16 + cl];
            } else {
                int k = q * 8 + j;
                f = W[k * HID + hf * 16 + cl];
            }
            v[j] = (__bf16)f;
        }
        *(bf16x8*)(pp.ws + slot * 1024 + l * 16) = v;
    } else if (t < 56 * 64 + 128) {
        int i = t - 56 * 64;
        int g = i >> 5, col = i & 31;
        const float* B  = g==0 ? pp.b0  : g==1 ? pp.b1  : g==2 ? pp.b2  : pp.b3;
        const float* Bc = g==0 ? pp.bc0 : g==1 ? pp.bc1 : g==2 ? pp.bc2 : pp.bc3;
        ((float*)(pp.ws + FRAG_BYTES))[i] = B[col] + Bc[col];
    }
}

struct Params {
    const float *x, *h, *c, *Wl, *bl;
    const char* ws;
    float *y, *h0o, *c0o;
    int n, nt;
};

// Stage one 32-row x tile (21120B contiguous) into LDS slot. Wave0: units 0-5
// (6 ops); waves 1-3: 5 ops each. Unit 20 overreads 384B into the next tile
// (harmless) except on the true last tile: mask lanes >= 40.
__device__ __forceinline__ void stage_x(const Params& p, char* smem, int bb,
                                        int tt, int w, int l, bool last) {
    char* buf = smem + bb * BUFSZ;
    const char* xc = (const char*)p.x + (size_t)tt * XBYTES + (size_t)l * 16;
    if (w == 0) {
#pragma unroll
        for (int i = 0; i < 6; ++i)
            gload_lds16(xc + i * 1024, buf + i * 1024);
    } else {
#pragma unroll
        for (int i = 0; i < 5; ++i) {
            int u = 1 + w * 5 + i;       // 6..20
            if (u != 20 || !last || l < 40)
                gload_lds16(xc + u * 1024, buf + u * 1024);
        }
    }
}

// 256 thr = 4 waves = {sub rows-half} x {hf cols-half}; each wave: 16 rows x
// 16 cols x all 4 gates. Depth-1 dbuf (R5 skeleton): per wave/iter the vmem
// order is [6 h/c loads][5-6 stage units][9 stores]; compiler's counted waits
// cover h/c without draining staging; manual vmcnt(9) at iter end == staging
// complete. x-only LDS (43.5KB) -> 3 blocks/CU = 12 waves/CU.
__global__ __launch_bounds__(256, 3) void gclstm_main(Params p) {
    __shared__ char smem[PYOFF + 512];
    float* py = (float*)(smem + PYOFF);   // [subwave 0..3][16 rows][2 cls]

    const int tid = threadIdx.x;
    const int w   = tid >> 6;
    const int sub = w >> 1, hf = w & 1;
    const int l   = tid & 63;
    const int cl  = l & 15, q = l >> 4;
    const int col = hf * 16 + cl;

    // weight fragments: this hf, all 4 gates (28 coalesced dwordx4)
    bf16x8 bw[4][7];
#pragma unroll
    for (int ks = 0; ks < 7; ++ks)
#pragma unroll
        for (int g = 0; g < 4; ++g)
            bw[g][ks] = *(const bf16x8*)(p.ws + (ks * 8 + g * 2 + hf) * 1024 + l * 16);

    const float* biasT = (const float*)(p.ws + FRAG_BYTES);
    float bias[4];
#pragma unroll
    for (int g = 0; g < 4; ++g) bias[g] = biasT[g * 32 + col];
    const float wl0 = p.Wl[col * 2 + 0];
    const float wl1 = p.Wl[col * 2 + 1];
    const float bl0 = p.bl[0], bl1 = p.bl[1];

    const int nt = p.nt, stride = gridDim.x;
    int t = blockIdx.x;
    if (t >= nt) return;

    const int lrow = sub * 16 + cl;       // A-frag row in tile
    const int drow = sub * 16 + 4 * q;    // D row base in tile

    // prologue: stage first x tile, drain, make visible
    stage_x(p, smem, 0, t, w, l, t == nt - 1);
    asm volatile("s_waitcnt vmcnt(0)" ::: "memory");
    __builtin_amdgcn_s_barrier();
    asm volatile("" ::: "memory");

    int cur = 0;
    while (true) {
        const int tn = t + stride;
        const bool more = (tn < nt);
        const long gbase = (long)t * TROWS;

        // ---- h/c register loads for CURRENT tile (issued before staging) ----
        float4 hA, hB;
        float cv[4];
        {
            const float* hr = p.h + (gbase + lrow) * HID + q * 8;
            hA = *(const float4*)hr;
            hB = *(const float4*)(hr + 4);
#pragma unroll
            for (int jj = 0; jj < 4; ++jj)
                cv[jj] = p.c[(gbase + drow + jj) * HID + col];
        }
        __builtin_amdgcn_sched_barrier(0);   // pin h/c loads BEFORE staging
        if (more) stage_x(p, smem, cur ^ 1, tn, w, l, tn == nt - 1);
        __builtin_amdgcn_sched_barrier(0);   // pin staging before consume

        // ---- consume x from LDS buf[cur] ----
        const float* xb = (const float*)(smem + cur * BUFSZ);
        const int rb = lrow * F_IN;

        bf16x8 af[7];
#pragma unroll
        for (int ks = 0; ks < 5; ++ks) {
            float v[8];
#pragma unroll
            for (int j = 0; j < 8; ++j) v[j] = xb[rb + ks * 32 + q * 8 + j];
#pragma unroll
            for (int j = 0; j < 8; ++j) af[ks][j] = (__bf16)v[j];
        }
        {   // ks=5 tail: k=160..164 on q==0 lanes; mask others
            bool qz = (q == 0);
            float t0 = xb[rb + 160], t1 = xb[rb + 161], t2 = xb[rb + 162];
            float t3 = xb[rb + 163], t4 = xb[rb + 164];
            af[5][0] = (__bf16)(qz ? t0 : 0.f);
            af[5][1] = (__bf16)(qz ? t1 : 0.f);
            af[5][2] = (__bf16)(qz ? t2 : 0.f);
            af[5][3] = (__bf16)(qz ? t3 : 0.f);
            af[5][4] = (__bf16)(qz ? t4 : 0.f);
            af[5][5] = (__bf16)0.f; af[5][6] = (__bf16)0.f; af[5][7] = (__bf16)0.f;
        }
        {   // h fragment from registers (compiler emits counted vmcnt wait)
            af[6][0]=(__bf16)hA.x; af[6][1]=(__bf16)hA.y; af[6][2]=(__bf16)hA.z; af[6][3]=(__bf16)hA.w;
            af[6][4]=(__bf16)hB.x; af[6][5]=(__bf16)hB.y; af[6][6]=(__bf16)hB.z; af[6][7]=(__bf16)hB.w;
        }

        f32x4 acc[4];
#pragma unroll
        for (int g = 0; g < 4; ++g) acc[g] = (f32x4){0.f, 0.f, 0.f, 0.f};
#pragma unroll
        for (int ks = 0; ks < 7; ++ks)
#pragma unroll
            for (int g = 0; g < 4; ++g)
                acc[g] = __builtin_amdgcn_mfma_f32_16x16x32_bf16(af[ks], bw[g][ks], acc[g], 0, 0, 0);

        // ---- epilogue: exactly 8 global stores + py LDS writes ----
#pragma unroll
        for (int jj = 0; jj < 4; ++jj) {
            float iv = fast_sigmoid(acc[0][jj] + bias[0]);
            float fv = fast_sigmoid(acc[1][jj] + bias[1]);
            float gv = fast_tanh   (acc[2][jj] + bias[2]);
            float ov = fast_sigmoid(acc[3][jj] + bias[3]);
            float c0 = fv * cv[jj] + iv * gv;
            float h0 = ov * fast_tanh(c0);
            long grow = gbase + drow + jj;
            p.c0o[grow * HID + col] = c0;
            p.h0o[grow * HID + col] = h0;
            float rl = fmaxf(h0, 0.f);
            float r0 = rl * wl0, r1 = rl * wl1;
            r0 += __shfl_xor(r0, 1); r0 += __shfl_xor(r0, 2);
            r0 += __shfl_xor(r0, 4); r0 += __shfl_xor(r0, 8);
            r1 += __shfl_xor(r1, 1); r1 += __shfl_xor(r1, 2);
            r1 += __shfl_xor(r1, 4); r1 += __shfl_xor(r1, 8);
            if (cl == 0) {
                py[((sub * 2 + hf) * 16 + 4 * q + jj) * 2 + 0] = r0;
                py[((sub * 2 + hf) * 16 + 4 * q + jj) * 2 + 1] = r1;
            }
        }
        asm volatile("s_waitcnt lgkmcnt(0)" ::: "memory");
        __builtin_amdgcn_s_barrier();   // B2: py visible across waves
        asm volatile("" ::: "memory");

        // ---- y: wave w stores values v = w*16 + l (1 store per wave) ----
        if (l < 16) {
            int v = w * 16 + l;
            int r = v >> 1, k = v & 1;
            int s2 = r >> 4, r16 = r & 15;
            float yv = py[((s2 * 2 + 0) * 16 + r16) * 2 + k]
                     + py[((s2 * 2 + 1) * 16 + r16) * 2 + k]
                     + (k ? bl1 : bl0);
            p.y[gbase * 2 + v] = yv;
        }

        if (!more) break;
        // all ops older than the 9 stores (== this iter's staging) complete
        asm volatile("s_waitcnt vmcnt(9)" ::: "memory");
        __builtin_amdgcn_s_barrier();   // B3: staged x visible + slot/py reuse
        asm volatile("" ::: "memory");
        cur ^= 1; t = tn;
    }
}

extern "C" void kernel_launch(void* const* d_in, const int* in_sizes, int n_in,
                              void* d_out, int out_size, void* d_ws, size_t ws_size,
                              hipStream_t stream) {
    PrepParams pp;
    pp.W0  = (const float*)d_in[5];
    pp.W1  = (const float*)d_in[6];
    pp.W2  = (const float*)d_in[7];
    pp.W3  = (const float*)d_in[8];
    pp.b0  = (const float*)d_in[9];
    pp.b1  = (const float*)d_in[10];
    pp.b2  = (const float*)d_in[11];
    pp.b3  = (const float*)d_in[12];
    pp.Wc0 = (const float*)d_in[13];
    pp.Wc1 = (const float*)d_in[14];
    pp.Wc2 = (const float*)d_in[15];
    pp.Wc3 = (const float*)d_in[16];
    pp.bc0 = (const float*)d_in[17];
    pp.bc1 = (const float*)d_in[18];
    pp.bc2 = (const float*)d_in[19];
    pp.bc3 = (const float*)d_in[20];
    pp.ws  = (char*)d_ws;
    hipLaunchKernelGGL(gclstm_prep, dim3(15), dim3(256), 0, stream, pp);

    Params p;
    p.x  = (const float*)d_in[0];
    p.h  = (const float*)d_in[3];
    p.c  = (const float*)d_in[4];
    p.Wl = (const float*)d_in[21];
    p.bl = (const float*)d_in[22];
    p.ws = (const char*)d_ws;

    const int n = in_sizes[0] / F_IN;   // 500000 (divisible by TROWS)
    p.n  = n;
    p.nt = n / TROWS;                   // 15625

    float* out = (float*)d_out;
    p.y   = out;
    p.h0o = out + (long)n * 2;
    p.c0o = out + (long)n * 2 + (long)n * HID;

    // 3 blocks/CU x 256 CUs (LDS 43.5KB, VGPR<=170 via launch_bounds)
    hipLaunchKernelGGL(gclstm_main, dim3(768), dim3(256), 0, stream, p);
}

// Round 10
// 131.133 us; speedup vs baseline: 1.5399x; 1.5399x over previous
//
#include <hip/hip_runtime.h>

#define F_IN 165
#define HID  32
#define TROWS 32                 // N=500000 = 32*15625 exact
#define XBYTES 21120             // source bytes per x tile (32*660)
#define HCB    4096              // source bytes per h/c tile (32*128)
// padded LDS layout: x rows 688B (22016), h/c rows 144B (4608)
#define XREG   22016
#define HOFF   22016
#define COFF   (HOFF + 4608)     // 26624
#define BUFSZ  (COFF + 4608)     // 31232
#define PYOFF  (2 * BUFSZ)       // 62464; + 1024 py -> 63488 B LDS

typedef __attribute__((ext_vector_type(8))) __bf16 bf16x8;
typedef __attribute__((ext_vector_type(4))) float  f32x4;

typedef __attribute__((address_space(1))) void as1_void;
typedef __attribute__((address_space(3))) void as3_void;

__device__ __forceinline__ void gload_lds16(const void* g, void* l) {
    __builtin_amdgcn_global_load_lds(
        reinterpret_cast<as1_void*>(reinterpret_cast<uintptr_t>(g)),
        reinterpret_cast<as3_void*>((uint32_t)reinterpret_cast<uintptr_t>(l)),
        16, 0, 0);
}
__device__ __forceinline__ void gload_lds4(const void* g, void* l) {
    __builtin_amdgcn_global_load_lds(
        reinterpret_cast<as1_void*>(reinterpret_cast<uintptr_t>(g)),
        reinterpret_cast<as3_void*>((uint32_t)reinterpret_cast<uintptr_t>(l)),
        4, 0, 0);
}

__device__ __forceinline__ float fast_sigmoid(float x) {
    return __builtin_amdgcn_rcpf(1.f + __builtin_amdgcn_exp2f(-1.4426950408889634f * x));
}
__device__ __forceinline__ float fast_tanh(float x) {
    return 1.f - 2.f * __builtin_amdgcn_rcpf(1.f + __builtin_amdgcn_exp2f(2.8853900817779268f * x));
}

// ---- workspace (prepacked): frag table 56 slots x 64 lanes x 16B; bias at +57344
#define FRAG_BYTES 57344

struct PrepParams {
    const float *W0, *W1, *W2, *W3;
    const float *Wc0, *Wc1, *Wc2, *Wc3;
    const float *b0, *b1, *b2, *b3;
    const float *bc0, *bc1, *bc2, *bc3;
    char* ws;
};

__global__ void gclstm_prep(PrepParams pp) {
    int t = blockIdx.x * 256 + threadIdx.x;
    if (t < 56 * 64) {
        int slot = t >> 6, l = t & 63;
        int ks = slot >> 3, g = (slot >> 1) & 3, hf = slot & 1;
        int cl = l & 15, q = l >> 4;
        const float* W = (ks < 6)
            ? (g==0 ? pp.W0  : g==1 ? pp.W1  : g==2 ? pp.W2  : pp.W3)
            : (g==0 ? pp.Wc0 : g==1 ? pp.Wc1 : g==2 ? pp.Wc2 : pp.Wc3);
        bf16x8 v;
#pragma unroll
        for (int j = 0; j < 8; ++j) {
            float f = 0.f;
            if (ks < 6) {
                int k = ks * 32 + q * 8 + j;
                if (k < F_IN) f = W[k * HID + hf * 16 + cl];
            } else {
                int k = q * 8 + j;
                f = W[k * HID + hf * 16 + cl];
            }
            v[j] = (__bf16)f;
        }
        *(bf16x8*)(pp.ws + slot * 1024 + l * 16) = v;
    } else if (t < 56 * 64 + 128) {
        int i = t - 56 * 64;
        int g = i >> 5, col = i & 31;
        const float* B  = g==0 ? pp.b0  : g==1 ? pp.b1  : g==2 ? pp.b2  : pp.b3;
        const float* Bc = g==0 ? pp.bc0 : g==1 ? pp.bc1 : g==2 ? pp.bc2 : pp.bc3;
        ((float*)(pp.ws + FRAG_BYTES))[i] = B[col] + Bc[col];
    }
}

struct Params {
    const float *x, *h, *c, *Wl, *bl;
    const char* ws;
    float *y, *h0o, *c0o;
    int n, nt;
};

// ---- staging: DMA with per-lane source-shift to build padded LDS rows ----
// x: padded byte o holds src byte o - 28*(o/688); 21 full 16B units + 2 size-4
// units covering [21504,22016) (row 31, r=31 fixed). h/c: o -> o - 16*(o/144);
// 4 full units + 2 size-4 units; tail lanes whose src would pass the tile end
// are clamped to 0 (their dests are pad, never read).
__device__ __forceinline__ void stage_tile(const Params& p, char* buf,
                                           long tt, int w, int l) {
    const char* xb = (const char*)p.x + tt * (long)XBYTES;
    const char* hb = (const char*)p.h + tt * (long)HCB;
    const char* cb = (const char*)p.c + tt * (long)HCB;
    if (w == 0) {
#pragma unroll
        for (int u = 0; u < 9; ++u) {
            int o = u * 1024 + l * 16;
            int r = ((o >> 4) * 1525) >> 16;          // o/688
            gload_lds16(xb + (o - 28 * r), buf + u * 1024);
        }
    } else if (w == 1) {
#pragma unroll
        for (int u = 9; u < 18; ++u) {
            int o = u * 1024 + l * 16;
            int r = ((o >> 4) * 1525) >> 16;
            gload_lds16(xb + (o - 28 * r), buf + u * 1024);
        }
    } else if (w == 2) {
#pragma unroll
        for (int u = 18; u < 21; ++u) {
            int o = u * 1024 + l * 16;
            int r = ((o >> 4) * 1525) >> 16;
            gload_lds16(xb + (o - 28 * r), buf + u * 1024);
        }
#pragma unroll
        for (int i = 0; i < 2; ++i) {                 // x row-31 tail, 4B grain
            int o = 21504 + i * 256 + l * 4;
            gload_lds4(xb + (o - 868), buf + 21504 + i * 256);
        }
#pragma unroll
        for (int u = 0; u < 2; ++u) {                 // h full units 0-1
            int o = u * 1024 + l * 16;
            int r = ((o >> 4) * 7282) >> 16;          // o/144
            gload_lds16(hb + (o - 16 * r), buf + HOFF + u * 1024);
        }
#pragma unroll
        for (int i = 0; i < 2; ++i) {                 // h tail
            int o = 4096 + i * 256 + l * 4;
            int r = ((o >> 4) * 7282) >> 16;
            int so = o - 16 * r;
            if (so > 4092) so = 0;                    // page-exact stream: clamp
            gload_lds4(hb + so, buf + HOFF + 4096 + i * 256);
        }
    } else {
#pragma unroll
        for (int u = 2; u < 4; ++u) {                 // h full units 2-3
            int o = u * 1024 + l * 16;
            int r = ((o >> 4) * 7282) >> 16;
            gload_lds16(hb + (o - 16 * r), buf + HOFF + u * 1024);
        }
#pragma unroll
        for (int u = 0; u < 4; ++u) {                 // c full units
            int o = u * 1024 + l * 16;
            int r = ((o >> 4) * 7282) >> 16;
            gload_lds16(cb + (o - 16 * r), buf + COFF + u * 1024);
        }
#pragma unroll
        for (int i = 0; i < 2; ++i) {                 // c tail
            int o = 4096 + i * 256 + l * 4;
            int r = ((o >> 4) * 7282) >> 16;
            int so = o - 16 * r;
            if (so > 4092) so = 0;
            gload_lds4(cb + so, buf + COFF + 4096 + i * 256);
        }
    }
}

// 256 thr = 4 waves = {sub rows-half} x {hf cols-half}. Depth-1 dbuf, all
// streams DMA'd (R5 skeleton). ONE barrier/iter: y-store delayed one tile via
// parity py; end-of-iter vmcnt(8) = "own staging complete" (per wave the vmem
// order is [y 0-1][stage 8-9][8 stores]; <=8 outstanding => y+stage done).
__global__ __launch_bounds__(256, 2) void gclstm_main(Params p) {
    __shared__ char smem[PYOFF + 1024];
    float* py = (float*)(smem + PYOFF);   // [parity][sub*2+hf][16 rows][2 cls]

    const int tid = threadIdx.x;
    const int w   = tid >> 6;
    const int sub = w >> 1, hf = w & 1;
    const int l   = tid & 63;
    const int cl  = l & 15, q = l >> 4;
    const int col = hf * 16 + cl;

    // weight fragments: this hf, all 4 gates (28 coalesced dwordx4)
    bf16x8 bw[4][7];
#pragma unroll
    for (int ks = 0; ks < 7; ++ks)
#pragma unroll
        for (int g = 0; g < 4; ++g)
            bw[g][ks] = *(const bf16x8*)(p.ws + (ks * 8 + g * 2 + hf) * 1024 + l * 16);

    const float* biasT = (const float*)(p.ws + FRAG_BYTES);
    float bias[4];
#pragma unroll
    for (int g = 0; g < 4; ++g) bias[g] = biasT[g * 32 + col];
    const float wl0 = p.Wl[col * 2 + 0];
    const float wl1 = p.Wl[col * 2 + 1];
    const float bl0 = p.bl[0], bl1 = p.bl[1];

    const int nt = p.nt, stride = gridDim.x;
    int t = blockIdx.x;
    if (t >= nt) return;

    const int lrow = sub * 16 + cl;
    const int drow = sub * 16 + 4 * q;

    // prologue
    stage_tile(p, smem, t, w, l);
    asm volatile("s_waitcnt vmcnt(0)" ::: "memory");
    __builtin_amdgcn_s_barrier();
    asm volatile("" ::: "memory");

    int cur = 0;
    int tprev = -1, pprev = 0;
    while (true) {
        const int tn = t + stride;
        const bool more = (tn < nt);

        // ---- delayed y-store for previous tile (reads py[pprev], fenced) ----
        if (tprev >= 0 && l < 16) {
            int v = w * 16 + l;
            int r = v >> 1, k = v & 1;
            int s2 = r >> 4, r16 = r & 15;
            float yv = py[((pprev * 4 + s2 * 2 + 0) * 16 + r16) * 2 + k]
                     + py[((pprev * 4 + s2 * 2 + 1) * 16 + r16) * 2 + k]
                     + (k ? bl1 : bl0);
            p.y[(long)tprev * TROWS * 2 + v] = yv;
        }

        if (more) stage_tile(p, smem + (cur ^ 1) * BUFSZ, tn, w, l);

        // ---- consume buf[cur]: aligned b128 reads from padded rows ----
        const char* buf  = smem + cur * BUFSZ;
        const char* xrow = buf + lrow * 688;
        bf16x8 af[7];
#pragma unroll
        for (int ks = 0; ks < 5; ++ks) {
            float4 a = *(const float4*)(xrow + ks * 128 + q * 32);
            float4 b = *(const float4*)(xrow + ks * 128 + q * 32 + 16);
            af[ks][0]=(__bf16)a.x; af[ks][1]=(__bf16)a.y; af[ks][2]=(__bf16)a.z; af[ks][3]=(__bf16)a.w;
            af[ks][4]=(__bf16)b.x; af[ks][5]=(__bf16)b.y; af[ks][6]=(__bf16)b.z; af[ks][7]=(__bf16)b.w;
        }
        {   // ks=5 tail: k=160..164 held by q==0 lanes (broadcast reads)
            float4 tq = *(const float4*)(xrow + 640);
            float t4  = *(const float*)(xrow + 656);
            bool qz = (q == 0);
            af[5][0] = (__bf16)(qz ? tq.x : 0.f);
            af[5][1] = (__bf16)(qz ? tq.y : 0.f);
            af[5][2] = (__bf16)(qz ? tq.z : 0.f);
            af[5][3] = (__bf16)(qz ? tq.w : 0.f);
            af[5][4] = (__bf16)(qz ? t4   : 0.f);
            af[5][5] = (__bf16)0.f; af[5][6] = (__bf16)0.f; af[5][7] = (__bf16)0.f;
        }
        {   // h fragment: padded 144B rows, balanced-bank b128
            const char* hrow = buf + HOFF + lrow * 144;
            float4 hA = *(const float4*)(hrow + q * 32);
            float4 hB = *(const float4*)(hrow + q * 32 + 16);
            af[6][0]=(__bf16)hA.x; af[6][1]=(__bf16)hA.y; af[6][2]=(__bf16)hA.z; af[6][3]=(__bf16)hA.w;
            af[6][4]=(__bf16)hB.x; af[6][5]=(__bf16)hB.y; af[6][6]=(__bf16)hB.z; af[6][7]=(__bf16)hB.w;
        }

        f32x4 acc[4];
#pragma unroll
        for (int g = 0; g < 4; ++g) acc[g] = (f32x4){0.f, 0.f, 0.f, 0.f};
#pragma unroll
        for (int ks = 0; ks < 7; ++ks)
#pragma unroll
            for (int g = 0; g < 4; ++g)
                acc[g] = __builtin_amdgcn_mfma_f32_16x16x32_bf16(af[ks], bw[g][ks], acc[g], 0, 0, 0);

        // ---- epilogue: 8 global stores + py[cur] LDS writes ----
        const long gbase = (long)t * TROWS;
#pragma unroll
        for (int jj = 0; jj < 4; ++jj) {
            const int r = drow + jj;
            float iv = fast_sigmoid(acc[0][jj] + bias[0]);
            float fv = fast_sigmoid(acc[1][jj] + bias[1]);
            float gv = fast_tanh   (acc[2][jj] + bias[2]);
            float ov = fast_sigmoid(acc[3][jj] + bias[3]);
            float cvv = *(const float*)(buf + COFF + r * 144 + col * 4);
            float c0 = fv * cvv + iv * gv;
            float h0 = ov * fast_tanh(c0);
            long grow = gbase + r;
            p.c0o[grow * HID + col] = c0;
            p.h0o[grow * HID + col] = h0;
            float rl = fmaxf(h0, 0.f);
            float r0 = rl * wl0, r1 = rl * wl1;
            r0 += __shfl_xor(r0, 1); r0 += __shfl_xor(r0, 2);
            r0 += __shfl_xor(r0, 4); r0 += __shfl_xor(r0, 8);
            r1 += __shfl_xor(r1, 1); r1 += __shfl_xor(r1, 2);
            r1 += __shfl_xor(r1, 4); r1 += __shfl_xor(r1, 8);
            if (cl == 0) {
                py[((cur * 4 + sub * 2 + hf) * 16 + 4 * q + jj) * 2 + 0] = r0;
                py[((cur * 4 + sub * 2 + hf) * 16 + 4 * q + jj) * 2 + 1] = r1;
            }
        }
        asm volatile("s_waitcnt lgkmcnt(0)" ::: "memory");

        if (!more) {
            __builtin_amdgcn_s_barrier();
            asm volatile("" ::: "memory");
            if (l < 16) {     // final tile's y
                int v = w * 16 + l;
                int r = v >> 1, k = v & 1;
                int s2 = r >> 4, r16 = r & 15;
                float yv = py[((cur * 4 + s2 * 2 + 0) * 16 + r16) * 2 + k]
                         + py[((cur * 4 + s2 * 2 + 1) * 16 + r16) * 2 + k]
                         + (k ? bl1 : bl0);
                p.y[gbase * 2 + v] = yv;
            }
            break;
        }
        // single per-iter sync: staging done + py visible + slot reuse safe
        asm volatile("s_waitcnt vmcnt(8)" ::: "memory");
        __builtin_amdgcn_s_barrier();
        asm volatile("" ::: "memory");
        tprev = t; pprev = cur;
        t = tn; cur ^= 1;
    }
}

extern "C" void kernel_launch(void* const* d_in, const int* in_sizes, int n_in,
                              void* d_out, int out_size, void* d_ws, size_t ws_size,
                              hipStream_t stream) {
    PrepParams pp;
    pp.W0  = (const float*)d_in[5];
    pp.W1  = (const float*)d_in[6];
    pp.W2  = (const float*)d_in[7];
    pp.W3  = (const float*)d_in[8];
    pp.b0  = (const float*)d_in[9];
    pp.b1  = (const float*)d_in[10];
    pp.b2  = (const float*)d_in[11];
    pp.b3  = (const float*)d_in[12];
    pp.Wc0 = (const float*)d_in[13];
    pp.Wc1 = (const float*)d_in[14];
    pp.Wc2 = (const float*)d_in[15];
    pp.Wc3 = (const float*)d_in[16];
    pp.bc0 = (const float*)d_in[17];
    pp.bc1 = (const float*)d_in[18];
    pp.bc2 = (const float*)d_in[19];
    pp.bc3 = (const float*)d_in[20];
    pp.ws  = (char*)d_ws;
    hipLaunchKernelGGL(gclstm_prep, dim3(15), dim3(256), 0, stream, pp);

    Params p;
    p.x  = (const float*)d_in[0];
    p.h  = (const float*)d_in[3];
    p.c  = (const float*)d_in[4];
    p.Wl = (const float*)d_in[21];
    p.bl = (const float*)d_in[22];
    p.ws = (const char*)d_ws;

    const int n = in_sizes[0] / F_IN;   // 500000 (divisible by TROWS)
    p.n  = n;
    p.nt = n / TROWS;                   // 15625

    float* out = (float*)d_out;
    p.y   = out;
    p.h0o = out + (long)n * 2;
    p.c0o = out + (long)n * 2 + (long)n * HID;

    // 2 blocks/CU x 256 CUs, all resident for the whole run
    hipLaunchKernelGGL(gclstm_main, dim3(512), dim3(256), 0, stream, p);
}